// Round 1
// baseline (841.695 us; speedup 1.0000x reference)
//
#include <hip/hip_runtime.h>

// Capsule layer, fused single kernel.
// B=512, T=2048, D=100, N*Dc=25, 4 routing iterations.
// One block per batch element; u_hat resides in registers (2 rows x 25 per thread).

#define NCAP 5
#define NJ 25          // NUM_CAPSULE * DIM_CAPSULE
#define NROUT 4
#define TT 2048
#define DD 100
#define TILE 256       // rows staged per LDS tile
#define XSS 101        // padded row stride (odd -> conflict-free strided reads)
#define NTH 1024
#define NWAVE 16

__global__ __launch_bounds__(NTH) void caps_fused(
    const float* __restrict__ gx,
    const float* __restrict__ gw,
    float* __restrict__ gout)
{
    __shared__ float xs[TILE * XSS];     // 103,424 B  x tile
    __shared__ float ut[TILE * NJ];      //  25,600 B  u_hat tile (k-split combine)
    __shared__ float red[NWAVE * NJ];    //   1,600 B  cross-wave reduction
    __shared__ float sv[NJ];             //     100 B  broadcast s-vector

    const int tid  = threadIdx.x;
    const int bidx = blockIdx.x;
    const int lane = tid & 63;
    const int wid  = __builtin_amdgcn_readfirstlane(tid >> 6);  // scalar wave id
    // matmul mapping: waves 0..14 active as (ks 0..2) x (jg 0..4); lane = row group
    const int ks   = wid / 5;
    const int jg   = wid % 5;
    const int jb   = jg * 5;
    const int k0   = (ks == 0) ? 0  : (ks == 1 ? 34 : 67);
    const int k1   = (ks == 0) ? 34 : (ks == 1 ? 67 : 100);

    const float* xb = gx + (size_t)bidx * (TT * DD);

    // per-thread u_hat: global rows 2*tid and 2*tid+1, all 25 columns
    float u[2][NJ];

    for (int c = 0; c < 8; ++c) {
        // ---- stage 256x100 x-tile into LDS (coalesced; write addr = i + i/100) ----
        const float* src = xb + c * (TILE * DD);
        #pragma unroll
        for (int s = 0; s < 25; ++s) {
            int i  = tid + s * NTH;          // 0..25599
            int rl = i / DD;                 // local row
            xs[i + rl] = src[i];             // rl*101 + (i - rl*100) == i + rl
        }
        __syncthreads();

        // ---- compute: rows {lane, lane+64, lane+128, lane+192}, cols jb..jb+4, k in [k0,k1) ----
        float acc[4][5];
        if (wid < 15) {
            #pragma unroll
            for (int r = 0; r < 4; ++r)
                #pragma unroll
                for (int j = 0; j < 5; ++j) acc[r][j] = 0.f;
            for (int k = k0; k < k1; ++k) {
                float wv[5];
                #pragma unroll
                for (int j = 0; j < 5; ++j) wv[j] = gw[k * NJ + jb + j];  // wave-uniform -> s_load
                #pragma unroll
                for (int r = 0; r < 4; ++r) {
                    float xv = xs[(lane + 64 * r) * XSS + k];             // bank stride 5: conflict-free
                    #pragma unroll
                    for (int j = 0; j < 5; ++j) acc[r][j] += xv * wv[j];
                }
            }
        }

        // ---- combine the 3 k-splits into ut ----
        if (wid < 15 && ks == 0) {
            #pragma unroll
            for (int r = 0; r < 4; ++r)
                #pragma unroll
                for (int j = 0; j < 5; ++j)
                    ut[(lane + 64 * r) * NJ + jb + j] = acc[r][j];
        }
        __syncthreads();
        if (wid < 15 && ks == 1) {
            #pragma unroll
            for (int r = 0; r < 4; ++r)
                #pragma unroll
                for (int j = 0; j < 5; ++j)
                    ut[(lane + 64 * r) * NJ + jb + j] += acc[r][j];
        }
        __syncthreads();
        if (wid < 15 && ks == 2) {
            #pragma unroll
            for (int r = 0; r < 4; ++r)
                #pragma unroll
                for (int j = 0; j < 5; ++j)
                    ut[(lane + 64 * r) * NJ + jb + j] += acc[r][j];
        }
        __syncthreads();

        // ---- owner readback: threads [128c, 128c+128) pull their 2 rows ----
        if ((tid >> 7) == c) {
            int tl = tid & 127;
            #pragma unroll
            for (int r = 0; r < 2; ++r)
                #pragma unroll
                for (int j = 0; j < NJ; ++j)
                    u[r][j] = ut[(2 * tl + r) * NJ + j];
        }
        __syncthreads();
    }

    // ---- routing: 4 iterations, all block-local ----
    float bv[2][NCAP];
    #pragma unroll
    for (int r = 0; r < 2; ++r)
        #pragma unroll
        for (int n = 0; n < NCAP; ++n) bv[r][n] = 0.f;

    for (int it = 0; it < NROUT; ++it) {
        float ps[NJ];
        #pragma unroll
        for (int j = 0; j < NJ; ++j) ps[j] = 0.f;

        #pragma unroll
        for (int r = 0; r < 2; ++r) {
            // softmax over n (b=0 at it=0 gives c=0.2 naturally)
            float mx = bv[r][0];
            #pragma unroll
            for (int n = 1; n < NCAP; ++n) mx = fmaxf(mx, bv[r][n]);
            float e[NCAP]; float se = 0.f;
            #pragma unroll
            for (int n = 0; n < NCAP; ++n) { e[n] = expf(bv[r][n] - mx); se += e[n]; }
            float ci = 1.f / se;
            #pragma unroll
            for (int n = 0; n < NCAP; ++n) {
                float cn = e[n] * ci;
                #pragma unroll
                for (int d = 0; d < 5; ++d) ps[n * 5 + d] += cn * u[r][n * 5 + d];
            }
        }

        // wave-level butterfly reduce of the 25 partials
        #pragma unroll
        for (int j = 0; j < NJ; ++j) {
            float v = ps[j];
            #pragma unroll
            for (int m = 1; m < 64; m <<= 1) v += __shfl_xor(v, m, 64);
            ps[j] = v;
        }
        if (lane == 0) {
            #pragma unroll
            for (int j = 0; j < NJ; ++j) red[wid * NJ + j] = ps[j];
        }
        __syncthreads();
        if (tid < NJ) {
            float s = 0.f;
            #pragma unroll
            for (int w = 0; w < NWAVE; ++w) s += red[w * NJ + tid];
            sv[tid] = s;
        }
        __syncthreads();

        if (it < NROUT - 1) {
            // squash + logit update, u in regs, sv broadcast from LDS
            float svr[NJ];
            #pragma unroll
            for (int j = 0; j < NJ; ++j) svr[j] = sv[j];
            float nr[NCAP];
            #pragma unroll
            for (int n = 0; n < NCAP; ++n) {
                float ss = 0.f;
                #pragma unroll
                for (int d = 0; d < 5; ++d) ss += svr[n * 5 + d] * svr[n * 5 + d];
                nr[n] = 1.f / sqrtf(ss + 1e-7f);
            }
            #pragma unroll
            for (int r = 0; r < 2; ++r)
                #pragma unroll
                for (int n = 0; n < NCAP; ++n) {
                    float t = 0.f;
                    #pragma unroll
                    for (int d = 0; d < 5; ++d) t += svr[n * 5 + d] * u[r][n * 5 + d];
                    bv[r][n] = nr[n] * t;
                }
        } else {
            // final squash + output (all LDS-indexed: no runtime reg-array index)
            if (tid < NJ) {
                int n = tid / 5;
                float ss = 0.f;
                #pragma unroll
                for (int d = 0; d < 5; ++d) ss += sv[n * 5 + d] * sv[n * 5 + d];
                gout[(size_t)bidx * NJ + tid] = sv[tid] * (1.f / sqrtf(ss + 1e-7f));
            }
        }
        __syncthreads();
    }
}

extern "C" void kernel_launch(void* const* d_in, const int* in_sizes, int n_in,
                              void* d_out, int out_size, void* d_ws, size_t ws_size,
                              hipStream_t stream) {
    const float* x = (const float*)d_in[0];
    const float* w = (const float*)d_in[1];
    float* out     = (float*)d_out;
    int B = in_sizes[0] / (TT * DD);   // 512
    caps_fused<<<dim3(B), dim3(NTH), 0, stream>>>(x, w, out);
}

// Round 2
// 745.301 us; speedup vs baseline: 1.1293x; 1.1293x over previous
//
#include <hip/hip_runtime.h>

// Capsule layer, fused single kernel — round 2.
// B=512, T=2048, D=100, N*Dc=25, 4 routing iterations.
// One block per batch element. u_hat in registers (2 rows x 25 per thread).
// Fixes vs r1: 128-VGPR budget (kills the 135MB scratch spill), float4 staging,
// no k-split (one (row,jgroup) per thread over full K), prefetch pipeline.

#define NCAP 5
#define NJ 25
#define NROUT 4
#define TT 2048
#define DD 100
#define TILE 128        // rows per chunk
#define NCHUNK 16       // 2048/128
#define XSS 101         // padded row stride: bank stride 5, conflict-free
#define NTH 1024
#define NWAVE 16

__global__ __launch_bounds__(NTH, 4) void caps_fused(
    const float* __restrict__ gx,
    const float* __restrict__ gw,
    float* __restrict__ gout)
{
    __shared__ float xs[TILE * XSS];   // 51,712 B  x tile
    __shared__ float ut[TILE * NJ];    // 12,800 B  u_hat tile
    __shared__ float red[NWAVE * NJ];  //  1,600 B  cross-wave reduce
    __shared__ float sv[NJ];           //    100 B  s-vector broadcast

    const int tid  = threadIdx.x;
    const int bidx = blockIdx.x;
    const int lane = tid & 63;
    const int wid  = __builtin_amdgcn_readfirstlane(tid >> 6);
    const int jg5  = __builtin_amdgcn_readfirstlane(tid >> 7) * 5;  // wave-uniform j-group*5
    const int rloc = tid & 127;                                     // local row for compute

    const float* xb = gx + (size_t)bidx * (TT * DD);

    float u[2][NJ];          // rows 2*tid, 2*tid+1 (owner = wave c at chunk c)
    float4 st0, st1, st2, st3;

    // prefetch chunk 0
    {
        const float4* s4 = (const float4*)xb;
        st0 = s4[tid]; st1 = s4[tid + 1024]; st2 = s4[tid + 2048];
        if (tid < 128) st3 = s4[tid + 3072];
    }

    for (int c = 0; c < NCHUNK; ++c) {
        __syncthreads();   // xs free (prev compute done), ut(c-1) complete

        // ---- drain staged regs -> xs (4 floats stay within one row: 100%4==0) ----
        {
            int e, rl, b;
            e = 4 * tid;          rl = e / DD; b = e + rl;
            xs[b] = st0.x; xs[b+1] = st0.y; xs[b+2] = st0.z; xs[b+3] = st0.w;
            e = 4 * (tid + 1024); rl = e / DD; b = e + rl;
            xs[b] = st1.x; xs[b+1] = st1.y; xs[b+2] = st1.z; xs[b+3] = st1.w;
            e = 4 * (tid + 2048); rl = e / DD; b = e + rl;
            xs[b] = st2.x; xs[b+1] = st2.y; xs[b+2] = st2.z; xs[b+3] = st2.w;
            if (tid < 128) {
                e = 4 * (tid + 3072); rl = e / DD; b = e + rl;
                xs[b] = st3.x; xs[b+1] = st3.y; xs[b+2] = st3.z; xs[b+3] = st3.w;
            }
        }
        // ---- owner wave c-1 pulls its u_hat rows (ut region, no conflict with xs) ----
        if (c > 0 && wid == c - 1) {
            #pragma unroll
            for (int r = 0; r < 2; ++r)
                #pragma unroll
                for (int j = 0; j < NJ; ++j)
                    u[r][j] = ut[(2 * lane + r) * NJ + j];
        }
        __syncthreads();   // xs ready; ut free for rewrite

        // ---- issue next chunk's global loads (overlap with compute below) ----
        if (c < NCHUNK - 1) {
            const float4* s4 = (const float4*)(xb + (c + 1) * (TILE * DD));
            st0 = s4[tid]; st1 = s4[tid + 1024]; st2 = s4[tid + 2048];
            if (tid < 128) st3 = s4[tid + 3072];
        }

        // ---- compute: threads 0..639, one (row, j-group), full K ----
        if (tid < 640) {
            float a0 = 0.f, a1 = 0.f, a2 = 0.f, a3 = 0.f, a4 = 0.f;
            const float* xrow = xs + rloc * XSS;
            const float* wp   = gw + jg5;
            #pragma unroll 4
            for (int k = 0; k < DD; ++k) {
                float xv = xrow[k];                  // bank stride 5: conflict-free
                const float* w5 = wp + k * NJ;       // wave-uniform -> s_load
                a0 += xv * w5[0]; a1 += xv * w5[1]; a2 += xv * w5[2];
                a3 += xv * w5[3]; a4 += xv * w5[4];
            }
            int ro = rloc * NJ + jg5;
            ut[ro+0] = a0; ut[ro+1] = a1; ut[ro+2] = a2; ut[ro+3] = a3; ut[ro+4] = a4;
        }
    }
    __syncthreads();
    if (wid == NCHUNK - 1) {
        #pragma unroll
        for (int r = 0; r < 2; ++r)
            #pragma unroll
            for (int j = 0; j < NJ; ++j)
                u[r][j] = ut[(2 * lane + r) * NJ + j];
    }

    // ---- routing: 4 iterations, block-local ----
    float bv[2][NCAP];
    #pragma unroll
    for (int r = 0; r < 2; ++r)
        #pragma unroll
        for (int n = 0; n < NCAP; ++n) bv[r][n] = 0.f;

    for (int it = 0; it < NROUT; ++it) {
        float ps[NJ];
        #pragma unroll
        for (int j = 0; j < NJ; ++j) ps[j] = 0.f;

        #pragma unroll
        for (int r = 0; r < 2; ++r) {
            float mx = bv[r][0];
            #pragma unroll
            for (int n = 1; n < NCAP; ++n) mx = fmaxf(mx, bv[r][n]);
            float e[NCAP]; float se = 0.f;
            #pragma unroll
            for (int n = 0; n < NCAP; ++n) { e[n] = expf(bv[r][n] - mx); se += e[n]; }
            float ci = 1.f / se;
            #pragma unroll
            for (int n = 0; n < NCAP; ++n) {
                float cn = e[n] * ci;
                #pragma unroll
                for (int d = 0; d < 5; ++d) ps[n * 5 + d] += cn * u[r][n * 5 + d];
            }
        }

        // wave butterfly + cross-wave reduce
        #pragma unroll
        for (int j = 0; j < NJ; ++j) {
            float v = ps[j];
            #pragma unroll
            for (int m = 1; m < 64; m <<= 1) v += __shfl_xor(v, m, 64);
            ps[j] = v;
        }
        if (lane == 0) {
            #pragma unroll
            for (int j = 0; j < NJ; ++j) red[wid * NJ + j] = ps[j];
        }
        __syncthreads();
        if (tid < NJ) {
            float s = 0.f;
            #pragma unroll
            for (int w = 0; w < NWAVE; ++w) s += red[w * NJ + tid];
            sv[tid] = s;
        }
        __syncthreads();

        if (it < NROUT - 1) {
            // squash norms from LDS (broadcast reads), logit update
            float nr[NCAP];
            #pragma unroll
            for (int n = 0; n < NCAP; ++n) {
                float ss = 0.f;
                #pragma unroll
                for (int d = 0; d < 5; ++d) ss += sv[n * 5 + d] * sv[n * 5 + d];
                nr[n] = 1.f / sqrtf(ss + 1e-7f);
            }
            #pragma unroll
            for (int r = 0; r < 2; ++r)
                #pragma unroll
                for (int n = 0; n < NCAP; ++n) {
                    float t = 0.f;
                    #pragma unroll
                    for (int d = 0; d < 5; ++d) t += sv[n * 5 + d] * u[r][n * 5 + d];
                    bv[r][n] = nr[n] * t;
                }
        } else {
            if (tid < NJ) {
                int n = tid / 5;
                float ss = 0.f;
                #pragma unroll
                for (int d = 0; d < 5; ++d) ss += sv[n * 5 + d] * sv[n * 5 + d];
                gout[(size_t)bidx * NJ + tid] = sv[tid] * (1.f / sqrtf(ss + 1e-7f));
            }
        }
        __syncthreads();
    }
}

extern "C" void kernel_launch(void* const* d_in, const int* in_sizes, int n_in,
                              void* d_out, int out_size, void* d_ws, size_t ws_size,
                              hipStream_t stream) {
    const float* x = (const float*)d_in[0];
    const float* w = (const float*)d_in[1];
    float* out     = (float*)d_out;
    int B = in_sizes[0] / (TT * DD);   // 512
    caps_fused<<<dim3(B), dim3(NTH), 0, stream>>>(x, w, out);
}

// Round 3
// 733.854 us; speedup vs baseline: 1.1470x; 1.0156x over previous
//
#include <hip/hip_runtime.h>

// Capsule layer, fused single kernel — round 3.
// B=512, T=2048, D=100, N*Dc=25, 4 routing iterations.
// One block per batch element; u_hat in registers (2 rows x 25 per thread).
//
// r2 post-mortem: compiler targeted 2 blocks/CU -> 64-VGPR budget -> u[2][25]
// spilled to scratch (236 MB writes). Fix: pin occupancy with
// amdgpu_waves_per_eu(4,4) (launch_bounds' 2nd arg is only a MIN), pad LDS
// past 80 KiB so 1 block/CU is the runtime limit regardless, and cut peak
// register demand in routing (per-capsule ps groups of 5 instead of ps[25]).

#define NCAP 5
#define NJ 25
#define NROUT 4
#define TT 2048
#define DD 100
#define TILE 128        // rows per chunk
#define NCHUNK 16       // 2048/128
#define XSS 101         // padded row stride: read bank stride 5 (odd) -> conflict-free
#define NTH 1024
#define NWAVE 16

__global__ __attribute__((amdgpu_waves_per_eu(4, 4))) __launch_bounds__(NTH)
void caps_fused(
    const float* __restrict__ gx,
    const float* __restrict__ gw,
    float* __restrict__ gout)
{
    __shared__ float xs[TILE * XSS];    // 51,712 B  x tile
    __shared__ float ut[TILE * NJ];     // 12,800 B  u_hat tile
    __shared__ float red[NWAVE * NJ];   //  1,600 B  cross-wave reduce
    __shared__ float sv[NJ];            //    100 B  s-vector broadcast
    __shared__ float occ_pad[4200];     // 16,800 B  -> total ~83 KB: forces 1 block/CU

    const int tid  = threadIdx.x;
    const int bidx = blockIdx.x;
    const int lane = tid & 63;
    const int wid  = __builtin_amdgcn_readfirstlane(tid >> 6);
    const int jg5  = __builtin_amdgcn_readfirstlane(tid >> 7) * 5;  // wave-uniform
    const int rloc = tid & 127;

    // opaque guard: keeps occ_pad allocated, never executes in practice
    if (gout == (float*)gw) occ_pad[0] = 1.f;

    const float* xb = gx + (size_t)bidx * (TT * DD);

    float u[2][NJ];          // rows 2*lane, 2*lane+1 of chunk wid (owner = wave c)
    float4 st0, st1, st2, st3;

    // prefetch chunk 0
    {
        const float4* s4 = (const float4*)xb;
        st0 = s4[tid]; st1 = s4[tid + 1024]; st2 = s4[tid + 2048];
        if (tid < 128) st3 = s4[tid + 3072];
    }

    for (int c = 0; c < NCHUNK; ++c) {
        __syncthreads();   // xs free (prev compute done)

        // ---- drain staged regs -> xs (float4 never crosses a row: 100%4==0) ----
        {
            int e, rl, b;
            e = 4 * tid;          rl = e / DD; b = e + rl;
            xs[b] = st0.x; xs[b+1] = st0.y; xs[b+2] = st0.z; xs[b+3] = st0.w;
            e = 4 * (tid + 1024); rl = e / DD; b = e + rl;
            xs[b] = st1.x; xs[b+1] = st1.y; xs[b+2] = st1.z; xs[b+3] = st1.w;
            e = 4 * (tid + 2048); rl = e / DD; b = e + rl;
            xs[b] = st2.x; xs[b+1] = st2.y; xs[b+2] = st2.z; xs[b+3] = st2.w;
            if (tid < 128) {
                e = 4 * (tid + 3072); rl = e / DD; b = e + rl;
                xs[b] = st3.x; xs[b+1] = st3.y; xs[b+2] = st3.z; xs[b+3] = st3.w;
            }
        }
        // ---- owner wave c-1 pulls its u_hat rows (ut not touched in this window) ----
        if (c > 0 && wid == c - 1) {
            #pragma unroll
            for (int r = 0; r < 2; ++r)
                #pragma unroll
                for (int j = 0; j < NJ; ++j)
                    u[r][j] = ut[(2 * lane + r) * NJ + j];
        }
        __syncthreads();   // xs ready; ut free for rewrite

        // ---- issue next chunk's global loads (overlap with compute) ----
        if (c < NCHUNK - 1) {
            const float4* s4 = (const float4*)(xb + (c + 1) * (TILE * DD));
            st0 = s4[tid]; st1 = s4[tid + 1024]; st2 = s4[tid + 2048];
            if (tid < 128) st3 = s4[tid + 3072];
        }

        // ---- compute: threads 0..639 -> one (row, j-group), full K ----
        if (tid < 640) {
            float a0 = 0.f, a1 = 0.f, a2 = 0.f, a3 = 0.f, a4 = 0.f;
            const float* xrow = xs + rloc * XSS;
            const float* wp   = gw + jg5;
            #pragma unroll 4
            for (int k = 0; k < DD; ++k) {
                float xv = xrow[k];                  // bank stride 5: conflict-free
                const float* w5 = wp + k * NJ;       // wave-uniform -> s_load
                a0 += xv * w5[0]; a1 += xv * w5[1]; a2 += xv * w5[2];
                a3 += xv * w5[3]; a4 += xv * w5[4];
            }
            int ro = rloc * NJ + jg5;
            ut[ro+0] = a0; ut[ro+1] = a1; ut[ro+2] = a2; ut[ro+3] = a3; ut[ro+4] = a4;
        }
    }
    __syncthreads();
    if (wid == NCHUNK - 1) {
        #pragma unroll
        for (int r = 0; r < 2; ++r)
            #pragma unroll
            for (int j = 0; j < NJ; ++j)
                u[r][j] = ut[(2 * lane + r) * NJ + j];
    }

    // ---- routing: 4 iterations, block-local ----
    float bv[2][NCAP];
    #pragma unroll
    for (int r = 0; r < 2; ++r)
        #pragma unroll
        for (int n = 0; n < NCAP; ++n) bv[r][n] = 0.f;

    for (int it = 0; it < NROUT; ++it) {
        // softmax coefficients per row (5-wide, in regs)
        float c0[2][NCAP];
        #pragma unroll
        for (int r = 0; r < 2; ++r) {
            float mx = bv[r][0];
            #pragma unroll
            for (int n = 1; n < NCAP; ++n) mx = fmaxf(mx, bv[r][n]);
            float se = 0.f;
            #pragma unroll
            for (int n = 0; n < NCAP; ++n) { c0[r][n] = expf(bv[r][n] - mx); se += c0[r][n]; }
            float ci = 1.f / se;
            #pragma unroll
            for (int n = 0; n < NCAP; ++n) c0[r][n] *= ci;
        }

        // per-capsule partials (5 live at a time), butterfly, cross-wave stage
        #pragma unroll
        for (int n = 0; n < NCAP; ++n) {
            float p[5];
            #pragma unroll
            for (int d = 0; d < 5; ++d)
                p[d] = c0[0][n] * u[0][n*5+d] + c0[1][n] * u[1][n*5+d];
            #pragma unroll
            for (int d = 0; d < 5; ++d) {
                float v = p[d];
                #pragma unroll
                for (int m = 1; m < 64; m <<= 1) v += __shfl_xor(v, m, 64);
                p[d] = v;
            }
            if (lane == 0) {
                #pragma unroll
                for (int d = 0; d < 5; ++d) red[wid * NJ + n*5 + d] = p[d];
            }
        }
        __syncthreads();
        if (tid < NJ) {
            float s = 0.f;
            #pragma unroll
            for (int w = 0; w < NWAVE; ++w) s += red[w * NJ + tid];
            sv[tid] = s;
        }
        __syncthreads();

        if (it < NROUT - 1) {
            // squash norms from LDS (broadcast reads), logit update
            float nr[NCAP];
            #pragma unroll
            for (int n = 0; n < NCAP; ++n) {
                float ss = 0.f;
                #pragma unroll
                for (int d = 0; d < 5; ++d) ss += sv[n * 5 + d] * sv[n * 5 + d];
                nr[n] = 1.f / sqrtf(ss + 1e-7f);
            }
            #pragma unroll
            for (int r = 0; r < 2; ++r)
                #pragma unroll
                for (int n = 0; n < NCAP; ++n) {
                    float t = 0.f;
                    #pragma unroll
                    for (int d = 0; d < 5; ++d) t += sv[n * 5 + d] * u[r][n * 5 + d];
                    bv[r][n] = nr[n] * t;
                }
        } else {
            if (tid < NJ) {
                int n = tid / 5;
                float ss = 0.f;
                #pragma unroll
                for (int d = 0; d < 5; ++d) ss += sv[n * 5 + d] * sv[n * 5 + d];
                gout[(size_t)bidx * NJ + tid] = sv[tid] * (1.f / sqrtf(ss + 1e-7f));
            }
        }
        __syncthreads();
    }
}

extern "C" void kernel_launch(void* const* d_in, const int* in_sizes, int n_in,
                              void* d_out, int out_size, void* d_ws, size_t ws_size,
                              hipStream_t stream) {
    const float* x = (const float*)d_in[0];
    const float* w = (const float*)d_in[1];
    float* out     = (float*)d_out;
    int B = in_sizes[0] / (TT * DD);   // 512
    caps_fused<<<dim3(B), dim3(NTH), 0, stream>>>(x, w, out);
}